// Round 3
// baseline (16427.531 us; speedup 1.0000x reference)
//
#include <hip/hip_runtime.h>

// LSTM-with-projection (ELMo LSTMP), persistent-kernel, fp32-class precision:
//  - 256 blocks x 256 threads, 1 block/CU (153KB LDS) -> all co-resident
//  - block owns 16 units (64 gate cols) + 2 projection cols
//  - phase A: z = [x_t;h] @ [Wk;R] via SPLIT fp16 MFMA: a = ah + al/2048,
//    products ah*bh (acc) and ah*bl + al*bh (accL, scaled 2048). Residuals
//    scaled x2048 to stay in fp16 normal range (no denormal flush risk).
//    Per-product err ~2^-21.5 -> dz ~ 5e-7 (fp32-class). Weight hi/lo
//    fragments live in registers (no per-step weight traffic).
//  - gates + cell state block-local (c in LDS, fp32)
//  - phase B: projection exact fp32: hpre fp32 (global), P transposed once to
//    PT[col][k] in workspace; per-wave k-split dots + shfl butterfly
//  - 2 grid barriers/step: threadfence(agent) + monotonic atomic counter

#define NBLK 256
#define NTHR 256
#define B_   32
#define S_   128
#define D_   512
#define U_   4096
#define PJ   512
#define G4   16384
#define PITCH 1032    // xh row pitch (fp16 elems): 516 dwords -> bank rotation
#define LSCALE 2048.0f
#define LINV   4.8828125e-4f   // 1/2048

typedef __attribute__((ext_vector_type(8))) _Float16 half8;
typedef __attribute__((ext_vector_type(4))) float floatx4;

__device__ __forceinline__ void split_h(float f, _Float16& hi, _Float16& lo) {
  _Float16 h = (_Float16)f;                  // RTNE
  hi = h;
  lo = (_Float16)((f - (float)h) * LSCALE);  // residual x2048: normal range
}

__device__ __forceinline__ void gsync(unsigned* bar) {
  __threadfence();              // release: waitcnt + L2 writeback (agent)
  __syncthreads();
  if (threadIdx.x == 0) {
    unsigned old = __hip_atomic_fetch_add(bar, 1u, __ATOMIC_RELAXED,
                                          __HIP_MEMORY_SCOPE_AGENT);
    unsigned target = (old / NBLK + 1u) * NBLK;   // monotonic counter
    while (__hip_atomic_load(bar, __ATOMIC_RELAXED,
                             __HIP_MEMORY_SCOPE_AGENT) < target)
      __builtin_amdgcn_s_sleep(1);
  }
  __syncthreads();
  __threadfence();              // acquire: invalidate stale L1/L2
}

__global__ __launch_bounds__(NTHR, 1)
void lstm_persistent(const float* __restrict__ x,
                     const float* __restrict__ Wk,
                     const float* __restrict__ R,
                     const float* __restrict__ bias,
                     const float* __restrict__ P,
                     float* __restrict__ out,
                     unsigned* __restrict__ bar,
                     float* __restrict__ hbuf,   // [32][512] f32 (zeroed)
                     float* __restrict__ hpre,   // [32][4096] f32
                     float* __restrict__ PT)     // [512][4096] f32 = P^T
{
  __shared__ __align__(16) _Float16 xh_hi[B_ * PITCH];  // 66048 B
  __shared__ __align__(16) _Float16 xh_lo[B_ * PITCH];  // 66048 B
  __shared__ __align__(16) float zb[2][64][36];         // 18432 B
  __shared__ float cst[512];                            //  2048 B
  __shared__ float biasL[64];

  const int tid  = threadIdx.x;
  const int blk  = blockIdx.x;
  const int lane = tid & 63;
  const int w    = tid >> 6;   // wave 0..3
  const int ch   = w & 1;      // col-half: 0 -> cols 0..31, 1 -> 32..63
  const int kh   = w >> 1;     // k-half:   0 -> x@Wk (k<512), 1 -> h@R

  // ---- one-time setup -------------------------------------------------
  if (tid < 64) {
    int g = tid >> 4, j = tid & 15;
    biasL[tid] = bias[g * U_ + blk * 16 + j];
  }
  cst[tid] = 0.f;
  cst[tid + 256] = 0.f;

  // transpose our 16 unit-rows of P into PT: PT[c][k] = P[k][c]
  for (int i = tid; i < 16 * PJ; i += NTHR) {
    int c  = i >> 4;
    int kr = i & 15;
    int k  = blk * 16 + kr;
    PT[(size_t)c * U_ + k] = P[(size_t)k * PJ + c];
  }

  // Weight B-fragments (split fp16) into registers.
  // B-frag (16x16x32): lane holds B[k=quad*8+j][n=lane&15].
  half8 bhi[2][16], blo[2][16];
  {
    const float* Wsrc = kh ? R : Wk;
    const int n = lane & 15, q = lane >> 4;
#pragma unroll
    for (int nt = 0; nt < 2; ++nt) {
      int cib  = ch * 32 + nt * 16 + n;                   // col-in-block 0..63
      int gcol = (cib >> 4) * U_ + blk * 16 + (cib & 15); // gate*4096 + unit
#pragma unroll
      for (int s = 0; s < 16; ++s) {
        half8 th, tl;
#pragma unroll
        for (int i = 0; i < 8; ++i) {
          int k = s * 32 + q * 8 + i;                     // 0..511 within half
          _Float16 hi, lo;
          split_h(Wsrc[(size_t)k * G4 + gcol], hi, lo);
          th[i] = hi; tl[i] = lo;
        }
        bhi[nt][s] = th;
        blo[nt][s] = tl;
      }
    }
  }
  __syncthreads();

  // ---- time loop ------------------------------------------------------
  for (int t = 0; t < S_; ++t) {
    // stage x_t (k<512) and h (k>=512) into xh_hi/xh_lo (split fp16)
#pragma unroll
    for (int it = 0; it < 16; ++it) {
      int c = tid + it * NTHR;          // 0..4095 chunks of 8
      int b = c >> 7, kc = c & 127;
      int kg = kc << 3;
      const float* src = (kg < D_) ? (x + (size_t)(b * S_ + t) * D_ + kg)
                                   : (hbuf + b * PJ + (kg - D_));
      float4 f0 = *(const float4*)src;
      float4 f1 = *(const float4*)(src + 4);
      half8 th, tl;
      _Float16 hi, lo;
      split_h(f0.x, hi, lo); th[0] = hi; tl[0] = lo;
      split_h(f0.y, hi, lo); th[1] = hi; tl[1] = lo;
      split_h(f0.z, hi, lo); th[2] = hi; tl[2] = lo;
      split_h(f0.w, hi, lo); th[3] = hi; tl[3] = lo;
      split_h(f1.x, hi, lo); th[4] = hi; tl[4] = lo;
      split_h(f1.y, hi, lo); th[5] = hi; tl[5] = lo;
      split_h(f1.z, hi, lo); th[6] = hi; tl[6] = lo;
      split_h(f1.w, hi, lo); th[7] = hi; tl[7] = lo;
      *(half8*)(xh_hi + b * PITCH + kg) = th;
      *(half8*)(xh_lo + b * PITCH + kg) = tl;
    }
    __syncthreads();

    // phase A: z-slice via split-fp16 MFMA.
    // acc  = sum ah*bh ; accL = sum (ah*bl + al*bh)  [scaled x2048]
    // A-frag: lane holds A[m=lane&15][k=quad*8+j].
    {
      floatx4 acc00 = {0.f, 0.f, 0.f, 0.f};
      floatx4 acc01 = acc00, acc10 = acc00, acc11 = acc00;
      floatx4 accL00 = acc00, accL01 = acc00, accL10 = acc00, accL11 = acc00;
      const int m_ = lane & 15, q = lane >> 4;
      const int kb = kh * D_;
#pragma unroll
      for (int s = 0; s < 16; ++s) {
        int ko = kb + s * 32 + q * 8;
        half8 ah0 = *(const half8*)(xh_hi + m_ * PITCH + ko);
        half8 ah1 = *(const half8*)(xh_hi + (16 + m_) * PITCH + ko);
        half8 al0 = *(const half8*)(xh_lo + m_ * PITCH + ko);
        half8 al1 = *(const half8*)(xh_lo + (16 + m_) * PITCH + ko);
        acc00 = __builtin_amdgcn_mfma_f32_16x16x32_f16(ah0, bhi[0][s], acc00, 0, 0, 0);
        acc01 = __builtin_amdgcn_mfma_f32_16x16x32_f16(ah0, bhi[1][s], acc01, 0, 0, 0);
        acc10 = __builtin_amdgcn_mfma_f32_16x16x32_f16(ah1, bhi[0][s], acc10, 0, 0, 0);
        acc11 = __builtin_amdgcn_mfma_f32_16x16x32_f16(ah1, bhi[1][s], acc11, 0, 0, 0);
        accL00 = __builtin_amdgcn_mfma_f32_16x16x32_f16(ah0, blo[0][s], accL00, 0, 0, 0);
        accL01 = __builtin_amdgcn_mfma_f32_16x16x32_f16(ah0, blo[1][s], accL01, 0, 0, 0);
        accL10 = __builtin_amdgcn_mfma_f32_16x16x32_f16(ah1, blo[0][s], accL10, 0, 0, 0);
        accL11 = __builtin_amdgcn_mfma_f32_16x16x32_f16(ah1, blo[1][s], accL11, 0, 0, 0);
        accL00 = __builtin_amdgcn_mfma_f32_16x16x32_f16(al0, bhi[0][s], accL00, 0, 0, 0);
        accL01 = __builtin_amdgcn_mfma_f32_16x16x32_f16(al0, bhi[1][s], accL01, 0, 0, 0);
        accL10 = __builtin_amdgcn_mfma_f32_16x16x32_f16(al1, bhi[0][s], accL10, 0, 0, 0);
        accL11 = __builtin_amdgcn_mfma_f32_16x16x32_f16(al1, bhi[1][s], accL11, 0, 0, 0);
      }
      // D-frag: col=lane&15, row=quad*4+reg. zb[kh][col][batch].
      int n  = lane & 15;
      int c0 = ch * 32 + n, c1 = ch * 32 + 16 + n;
      int r0 = q * 4,       r1 = 16 + q * 4;
#pragma unroll
      for (int i = 0; i < 4; ++i) {
        zb[kh][c0][r0 + i] = acc00[i] + accL00[i] * LINV;
        zb[kh][c1][r0 + i] = acc01[i] + accL01[i] * LINV;
        zb[kh][c0][r1 + i] = acc10[i] + accL10[i] * LINV;
        zb[kh][c1][r1 + i] = acc11[i] + accL11[i] * LINV;
      }
    }
    __syncthreads();

    // gates + cell update (block-local), hpre -> global fp32
#pragma unroll
    for (int pp = 0; pp < 2; ++pp) {
      int p = tid + pp * NTHR;          // 0..511
      int b = p >> 4, j = p & 15;       // batch, unit-in-block
      float zi = zb[0][j][b]      + zb[1][j][b]      + biasL[j];
      float zf = zb[0][16 + j][b] + zb[1][16 + j][b] + biasL[16 + j];
      float zc = zb[0][32 + j][b] + zb[1][32 + j][b] + biasL[32 + j];
      float zo = zb[0][48 + j][b] + zb[1][48 + j][b] + biasL[48 + j];
      float ig = fminf(fmaxf(0.2f * zi + 0.5f, 0.f), 1.f);
      float fg = fminf(fmaxf(0.2f * zf + 0.5f, 0.f), 1.f);
      float og = fminf(fmaxf(0.2f * zo + 0.5f, 0.f), 1.f);
      float cn = fg * cst[p] + ig * tanhf(zc);
      float hp = og * tanhf(cn);                 // uses UNCLIPPED c
      cst[p] = fminf(fmaxf(cn, -3.f), 3.f);      // cell clip
      hpre[b * U_ + blk * 16 + j] = hp;
    }
    gsync(bar);   // hpre complete, visible device-wide

    // phase B (exact fp32): out[b][pc] = clip(sum_k hpre[b][k]*PT[pc][k], +-3)
    // wave w owns batches w*8..w*8+7; 8 lanes (kl) split k interleaved.
    {
      int bb = (w << 3) + (lane >> 3);  // batch 0..31
      int kl = lane & 7;                // k-lane 0..7
      const float* hrow = hpre + bb * U_;
      const float* p0   = PT + (size_t)(blk * 2 + 0) * U_;
      const float* p1   = PT + (size_t)(blk * 2 + 1) * U_;
      float a0x = 0.f, a0y = 0.f, a0z = 0.f, a0w = 0.f;
      float a1x = 0.f, a1y = 0.f, a1z = 0.f, a1w = 0.f;
#pragma unroll 4
      for (int i = 0; i < 128; ++i) {
        int k = (kl << 2) + (i << 5);   // 8 lanes cover 32 consecutive k
        float4 hv = *(const float4*)(hrow + k);
        float4 v0 = *(const float4*)(p0 + k);
        float4 v1 = *(const float4*)(p1 + k);
        a0x = fmaf(hv.x, v0.x, a0x); a0y = fmaf(hv.y, v0.y, a0y);
        a0z = fmaf(hv.z, v0.z, a0z); a0w = fmaf(hv.w, v0.w, a0w);
        a1x = fmaf(hv.x, v1.x, a1x); a1y = fmaf(hv.y, v1.y, a1y);
        a1z = fmaf(hv.z, v1.z, a1z); a1w = fmaf(hv.w, v1.w, a1w);
      }
      float a0 = (a0x + a0y) + (a0z + a0w);
      float a1 = (a1x + a1y) + (a1z + a1w);
#pragma unroll
      for (int m = 1; m < 8; m <<= 1) {   // butterfly over 8 kl-lanes
        a0 += __shfl_xor(a0, m, 64);
        a1 += __shfl_xor(a1, m, 64);
      }
      if (kl == 0) {
        float h0 = fminf(fmaxf(a0, -3.f), 3.f);
        float h1 = fminf(fmaxf(a1, -3.f), 3.f);
        float2 hv2 = make_float2(h0, h1);
        *(float2*)(out + (size_t)(bb * S_ + t) * PJ + blk * 2) = hv2;
        *(float2*)(hbuf + bb * PJ + blk * 2) = hv2;
      }
    }
    gsync(bar);   // h complete before next step's staging
  }
}

extern "C" void kernel_launch(void* const* d_in, const int* in_sizes, int n_in,
                              void* d_out, int out_size, void* d_ws, size_t ws_size,
                              hipStream_t stream) {
  const float* x_   = (const float*)d_in[0];
  const float* Wk   = (const float*)d_in[1];
  const float* R_   = (const float*)d_in[2];
  const float* bias = (const float*)d_in[3];
  const float* P_   = (const float*)d_in[4];
  float* out = (float*)d_out;

  unsigned char* ws = (unsigned char*)d_ws;
  unsigned* bar = (unsigned*)ws;                           // @0      (1 KB)
  float* hbuf   = (float*)(ws + 1024);                     // 64 KB
  float* hpre   = (float*)(ws + 1024 + 65536);             // 512 KB
  float* PT     = (float*)(ws + 1024 + 65536 + 524288);    // 8 MB

  // zero barrier counter + initial h state every launch
  hipMemsetAsync(d_ws, 0, 1024 + 65536, stream);

  lstm_persistent<<<dim3(NBLK), dim3(NTHR), 0, stream>>>(
      x_, Wk, R_, bias, P_, out, bar, hbuf, hpre, PT);
}